// Round 3
// baseline (280.335 us; speedup 1.0000x reference)
//
#include <hip/hip_runtime.h>
#include <hip/hip_fp16.h>
#include <cstdint>
#include <cstddef>

#define DEV __device__ __forceinline__

namespace {

constexpr float SCALE  = 0.35355339059327373f;  // 8^-0.5
constexpr float RATIO  = 63.0f / 127.0f;        // grid->input scale
constexpr float RANGEF = 11.0f;
constexpr float EPS    = 1e-6f;

DEV float fget(const float4& v, int c) {
  return c == 0 ? v.x : (c == 1 ? v.y : (c == 2 ? v.z : v.w));
}
DEV void fax(float4& a, float s, const float4& b) {
  a.x = fmaf(s, b.x, a.x); a.y = fmaf(s, b.y, a.y);
  a.z = fmaf(s, b.z, a.z); a.w = fmaf(s, b.w, a.w);
}
DEV void unpack8(float4 raw, float* f) {
  union { float4 v; __half2 h[4]; } u; u.v = raw;
  #pragma unroll
  for (int j = 0; j < 4; ++j) {
    float2 t = __half22float2(u.h[j]);
    f[2 * j] = t.x; f[2 * j + 1] = t.y;
  }
}

// ---- repack weights -------------------------------------------------------
// wT[(j*9+tap)*18+o]=off_w[o][j][tap]; dwT[tap*16+j]=dw_w[j][tap];
// wqT[c*32+o]=wq[o*128+c]; wkT same.
__global__ __launch_bounds__(256) void k_repack(
    const float* __restrict__ offw, const float* __restrict__ dww,
    const float* __restrict__ wq, const float* __restrict__ wk,
    float* __restrict__ wT, float* __restrict__ dwT,
    float* __restrict__ wqT, float* __restrict__ wkT) {
  for (int idx = threadIdx.x; idx < 18 * 16 * 9; idx += 256) {
    int o = idx / 144, r = idx % 144, j = r / 9, tap = r % 9;
    wT[(j * 9 + tap) * 18 + o] = offw[idx];
  }
  for (int idx = threadIdx.x; idx < 144; idx += 256) {
    int j = idx / 9, tap = idx % 9;
    dwT[tap * 16 + j] = dww[idx];
  }
  for (int idx = threadIdx.x; idx < 4096; idx += 256) {
    int c = idx >> 5, o = idx & 31;
    wqT[c * 32 + o] = wq[o * 128 + c];
    wkT[c * 32 + o] = wk[o * 128 + c];
  }
}

// ---- transpose x (B,128,64,64) -> vH fp16 (B,4096,128) ---------------------
__global__ __launch_bounds__(256) void k_transpose(const float* __restrict__ x,
                                                   __half* __restrict__ vH) {
  __shared__ float tile[128 * 65];
  int b = blockIdx.x >> 6, y = blockIdx.x & 63;
  const float* xp = x + (size_t)b * 128 * 4096 + (size_t)y * 64;
  int xc = threadIdx.x & 63, cb = threadIdx.x >> 6;
  #pragma unroll
  for (int i = 0; i < 32; ++i) {
    int c = cb * 32 + i;
    tile[c * 65 + xc] = xp[(size_t)c * 4096 + xc];
  }
  __syncthreads();
  int p = threadIdx.x >> 2, c0 = (threadIdx.x & 3) * 32;
  __half* op = vH + ((size_t)b * 4096 + (size_t)y * 64 + p) * 128 + c0;
  #pragma unroll
  for (int i = 0; i < 32; i += 8) {
    union { float4 f; __half2 h[4]; } u;
    #pragma unroll
    for (int j = 0; j < 4; ++j)
      u.h[j] = __floats2half2_rn(tile[(c0 + i + 2 * j) * 65 + p],
                                 tile[(c0 + i + 2 * j + 1) * 65 + p]);
    *(float4*)(op + i) = u.f;
  }
}

// ---- channel-LN + q/k projection (16 outputs per thread) -------------------
// sub = blockIdx&3: bit1 -> q(0)/k(1), bit0 -> output half
__global__ __launch_bounds__(256) void k_lnproj(
    const float* __restrict__ x, const float* __restrict__ lnw,
    const float* __restrict__ lnb, const float* __restrict__ wqT,
    const float* __restrict__ wkT, float* __restrict__ qT,
    __half* __restrict__ kH) {
  int sub = blockIdx.x & 3;
  int isk = sub >> 1, oh = sub & 1;
  int pos = (blockIdx.x >> 2) * 256 + threadIdx.x;  // [0, B*4096)
  int b = pos >> 12, sp = pos & 4095;
  const float* xp = x + (size_t)b * 128 * 4096 + sp;

  float s = 0.f, ss = 0.f;
  #pragma unroll
  for (int c = 0; c < 128; ++c) {
    float v = xp[(size_t)c * 4096];
    s += v; ss = fmaf(v, v, ss);
  }
  float mean = s * (1.f / 128.f);
  float var = ss * (1.f / 128.f) - mean * mean;
  float rstd = rsqrtf(var + EPS);

  const float* w = (isk ? wkT : wqT) + oh * 16;
  float acc[16];
  #pragma unroll
  for (int o = 0; o < 16; ++o) acc[o] = 0.f;
  #pragma unroll 4
  for (int c = 0; c < 128; ++c) {
    float xn = (xp[(size_t)c * 4096] - mean) * rstd * lnw[c] + lnb[c];
    const float* wr = w + c * 32;
    #pragma unroll
    for (int o = 0; o < 16; ++o) acc[o] = fmaf(wr[o], xn, acc[o]);
  }
  if (!isk) {
    float* op = qT + (size_t)pos * 32 + oh * 16;
    #pragma unroll
    for (int i = 0; i < 16; i += 4)
      *(float4*)(op + i) = make_float4(acc[i], acc[i + 1], acc[i + 2], acc[i + 3]);
  } else {
    __half* op = kH + (size_t)pos * 32 + oh * 16;
    #pragma unroll
    for (int i = 0; i < 16; i += 8) {
      union { float4 f; __half2 h[4]; } u;
      #pragma unroll
      for (int j = 0; j < 4; ++j)
        u.h[j] = __floats2half2_rn(acc[i + 2 * j], acc[i + 2 * j + 1]);
      *(float4*)(op + i) = u.f;
    }
  }
}

// ---- bilinear 64->128 align_corners resize: qT -> qrT ----------------------
__global__ __launch_bounds__(256) void k_resize(const float* __restrict__ qT,
                                                float* __restrict__ qrT) {
  int tid = blockIdx.x * 256 + threadIdx.x;
  int b = tid >> 14, rem = tid & 16383;
  int oy = rem >> 7, ox = rem & 127;
  float ys = oy * RATIO, xs = ox * RATIO;
  float yf = floorf(ys), xf = floorf(xs);
  int y0 = (int)yf, x0 = (int)xf;
  int y1 = min(y0 + 1, 63), x1 = min(x0 + 1, 63);
  float wy = ys - yf, wx = xs - xf;
  const float4* p00 = (const float4*)(qT + ((size_t)b * 4096 + y0 * 64 + x0) * 32);
  const float4* p01 = (const float4*)(qT + ((size_t)b * 4096 + y0 * 64 + x1) * 32);
  const float4* p10 = (const float4*)(qT + ((size_t)b * 4096 + y1 * 64 + x0) * 32);
  const float4* p11 = (const float4*)(qT + ((size_t)b * 4096 + y1 * 64 + x1) * 32);
  float w00 = (1.f - wy) * (1.f - wx), w01 = (1.f - wy) * wx;
  float w10 = wy * (1.f - wx), w11 = wy * wx;
  float4* op = (float4*)(qrT + ((size_t)b * 16384 + rem) * 32);
  #pragma unroll
  for (int i = 0; i < 8; ++i) {
    float4 r = {0.f, 0.f, 0.f, 0.f};
    fax(r, w00, p00[i]); fax(r, w01, p01[i]);
    fax(r, w10, p10[i]); fax(r, w11, p11[i]);
    op[i] = r;
  }
}

// ---- depthwise 3x3 + group channel-LN + SiLU: qrT -> tT --------------------
__global__ __launch_bounds__(256) void k_dwln(
    const float* __restrict__ qrT, const float* __restrict__ dwT,
    const float* __restrict__ olnw, const float* __restrict__ olnb,
    float* __restrict__ tT) {
  int tid = blockIdx.x * 256 + threadIdx.x;
  int b = tid >> 14, rem = tid & 16383;
  int oy = rem >> 7, ox = rem & 127;
  float4 a[8] = {};
  #pragma unroll
  for (int kh = 0; kh < 3; ++kh) {
    int ty = oy + kh - 1;
    if (ty < 0 || ty >= 128) continue;
    #pragma unroll
    for (int kw = 0; kw < 3; ++kw) {
      int tx = ox + kw - 1;
      if (tx < 0 || tx >= 128) continue;
      int tap = kh * 3 + kw;
      const float4* p =
          (const float4*)(qrT + ((size_t)b * 16384 + (size_t)ty * 128 + tx) * 32);
      #pragma unroll
      for (int i = 0; i < 8; ++i) {
        float4 v = p[i];
        const float* dw = dwT + tap * 16 + (i & 3) * 4;
        a[i].x = fmaf(dw[0], v.x, a[i].x);
        a[i].y = fmaf(dw[1], v.y, a[i].y);
        a[i].z = fmaf(dw[2], v.z, a[i].z);
        a[i].w = fmaf(dw[3], v.w, a[i].w);
      }
    }
  }
  float4* op = (float4*)(tT + ((size_t)b * 16384 + rem) * 32);
  #pragma unroll
  for (int g = 0; g < 2; ++g) {
    float s = 0.f;
    #pragma unroll
    for (int i = 0; i < 4; ++i) {
      float4 v = a[g * 4 + i];
      s += v.x + v.y + v.z + v.w;
    }
    float mean = s * (1.f / 16.f);
    float var = 0.f;
    #pragma unroll
    for (int i = 0; i < 4; ++i) {
      float4 v = a[g * 4 + i];
      var += (v.x - mean) * (v.x - mean) + (v.y - mean) * (v.y - mean) +
             (v.z - mean) * (v.z - mean) + (v.w - mean) * (v.w - mean);
    }
    float rstd = rsqrtf(var * (1.f / 16.f) + EPS);
    #pragma unroll
    for (int i = 0; i < 4; ++i) {
      float4 v = a[g * 4 + i];
      int j0 = i * 4;
      float4 r;
      r.x = (v.x - mean) * rstd * olnw[j0 + 0] + olnb[j0 + 0];
      r.y = (v.y - mean) * rstd * olnw[j0 + 1] + olnb[j0 + 1];
      r.z = (v.z - mean) * rstd * olnw[j0 + 2] + olnb[j0 + 2];
      r.w = (v.w - mean) * rstd * olnw[j0 + 3] + olnb[j0 + 3];
      r.x = r.x / (1.f + expf(-r.x));
      r.y = r.y / (1.f + expf(-r.y));
      r.z = r.z / (1.f + expf(-r.z));
      r.w = r.w / (1.f + expf(-r.w));
      op[g * 4 + i] = r;
    }
  }
}

// ---- 16->18 3x3 conv + tanh*RANGE + abs coords: tT -> crd ------------------
__global__ __launch_bounds__(256) void k_off(
    const float* __restrict__ tT, const float* __restrict__ wT,
    const float* __restrict__ offb, float* __restrict__ crd) {
  int tid = blockIdx.x * 256 + threadIdx.x;
  int bg = tid >> 13, rem = tid & 8191;
  int oy = rem >> 6, ox = rem & 63;
  int b = bg >> 1, g = bg & 1;
  float a0[18], a1[18];
  #pragma unroll
  for (int o = 0; o < 18; ++o) { a0[o] = 0.f; a1[o] = 0.f; }
  #pragma unroll
  for (int kh = 0; kh < 3; ++kh) {
    int ty = oy + kh - 1;
    if (ty < 0 || ty >= 128) continue;
    const float* base = tT + ((size_t)b * 16384 + (size_t)ty * 128) * 32 + g * 16;
    #pragma unroll
    for (int kw = 0; kw < 3; ++kw) {
      int tap = kh * 3 + kw;
      int tx0 = ox + kw - 1, tx1 = tx0 + 64;
      float4 A[4] = {}, Bv[4] = {};
      if (tx0 >= 0) {
        const float4* p = (const float4*)(base + (size_t)tx0 * 32);
        A[0] = p[0]; A[1] = p[1]; A[2] = p[2]; A[3] = p[3];
      }
      if (tx1 < 128) {
        const float4* p = (const float4*)(base + (size_t)tx1 * 32);
        Bv[0] = p[0]; Bv[1] = p[1]; Bv[2] = p[2]; Bv[3] = p[3];
      }
      #pragma unroll
      for (int j = 0; j < 16; ++j) {
        float f0 = fget(A[j >> 2], j & 3);
        float f1 = fget(Bv[j >> 2], j & 3);
        const float* wrow = wT + (size_t)(j * 9 + tap) * 18;
        #pragma unroll
        for (int o = 0; o < 18; ++o) {
          float w = wrow[o];
          a0[o] = fmaf(w, f0, a0[o]);
          a1[o] = fmaf(w, f1, a1[o]);
        }
      }
    }
  }
  #pragma unroll
  for (int o = 0; o < 18; ++o) {
    float bo = offb[o];
    a0[o] += bo; a1[o] += bo;
  }
  size_t pbase = (size_t)bg * 16384 + (size_t)oy * 128 + ox;
  float* c0 = crd + pbase * 18;
  float* c1 = crd + (pbase + 64) * 18;
  #pragma unroll
  for (int kp = 0; kp < 9; ++kp) {
    float byo = (float)(kp / 3 - 1), bxo = (float)(kp % 3 - 1);
    float ay0 = tanhf(a0[2 * kp]) * RANGEF + byo + (float)oy;
    float ax0 = tanhf(a0[2 * kp + 1]) * RANGEF + bxo + (float)ox;
    c0[2 * kp] = ay0 * RATIO;
    c0[2 * kp + 1] = ax0 * RATIO;
    float ay1 = tanhf(a1[2 * kp]) * RANGEF + byo + (float)oy;
    float ax1 = tanhf(a1[2 * kp + 1]) * RANGEF + bxo + (float)(ox + 64);
    c1[2 * kp] = ay1 * RATIO;
    c1[2 * kp + 1] = ax1 * RATIO;
  }
}

// ---- attention weights: thread = (b,g,pos), both heads of the group --------
__global__ __launch_bounds__(256) void k_wgt(
    const float* __restrict__ qrT, const __half* __restrict__ kH,
    const float* __restrict__ crd, const float* __restrict__ rpb,
    float* __restrict__ attw) {
  int tid = blockIdx.x * 256 + threadIdx.x;  // [0, B*2*16384)
  int pos = tid & 16383;
  int bg = tid >> 14;
  int g = bg & 1, b = bg >> 1;

  float q[16];
  const float4* qp = (const float4*)(qrT + ((size_t)b * 16384 + pos) * 32 + g * 16);
  #pragma unroll
  for (int i = 0; i < 4; ++i) {
    float4 v = qp[i];
    q[4 * i + 0] = v.x * SCALE; q[4 * i + 1] = v.y * SCALE;
    q[4 * i + 2] = v.z * SCALE; q[4 * i + 3] = v.w * SCALE;
  }
  const float* cp = crd + ((size_t)bg * 16384 + pos) * 18;
  const __half* kb = kH + (size_t)b * 4096 * 32 + g * 16;

  float l0[9], l1[9];
  #pragma unroll
  for (int kp = 0; kp < 9; ++kp) {
    float iy = cp[2 * kp], ix = cp[2 * kp + 1];
    float yf = floorf(iy), xf = floorf(ix);
    float wy = iy - yf, wx = ix - xf;
    int y0 = (int)yf, x0 = (int)xf;
    float a0 = 0.f, a1 = 0.f;
    #pragma unroll
    for (int dy = 0; dy < 2; ++dy) {
      int yy = y0 + dy;
      float wyv = dy ? wy : 1.f - wy;
      #pragma unroll
      for (int dx = 0; dx < 2; ++dx) {
        int xx = x0 + dx;
        bool valid = ((unsigned)yy < 64u) && ((unsigned)xx < 64u);
        float w = valid ? wyv * (dx ? wx : 1.f - wx) : 0.f;
        int idx = valid ? yy * 64 + xx : 0;
        const float4* kr = (const float4*)(kb + (size_t)idx * 32);
        float kf[16];
        unpack8(kr[0], kf); unpack8(kr[1], kf + 8);
        float d0 = 0.f, d1 = 0.f;
        #pragma unroll
        for (int e = 0; e < 8; ++e) {
          d0 = fmaf(q[e], kf[e], d0);
          d1 = fmaf(q[8 + e], kf[8 + e], d1);
        }
        a0 = fmaf(w, d0, a0);
        a1 = fmaf(w, d1, a1);
      }
    }
    const float* rp0 = rpb + (size_t)((2 * g) * 9 + kp) * 8;
    const float* rp1 = rpb + (size_t)((2 * g + 1) * 9 + kp) * 8;
    #pragma unroll
    for (int e = 0; e < 8; ++e) {
      a0 = fmaf(q[e], rp0[e], a0);
      a1 = fmaf(q[8 + e], rp1[e], a1);
    }
    l0[kp] = a0; l1[kp] = a1;
  }

  float m0 = l0[0], m1 = l1[0];
  #pragma unroll
  for (int kp = 1; kp < 9; ++kp) { m0 = fmaxf(m0, l0[kp]); m1 = fmaxf(m1, l1[kp]); }
  float s0 = 0.f, s1 = 0.f;
  #pragma unroll
  for (int kp = 0; kp < 9; ++kp) {
    l0[kp] = expf(l0[kp] - m0); s0 += l0[kp];
    l1[kp] = expf(l1[kp] - m1); s1 += l1[kp];
  }
  float i0 = 1.f / s0, i1 = 1.f / s1;
  float* wp = attw + ((size_t)b * 16384 + pos) * 36 + g * 18;
  #pragma unroll
  for (int kp = 0; kp < 9; ++kp) {
    wp[kp] = l0[kp] * i0;
    wp[9 + kp] = l1[kp] * i1;
  }
}

// ---- v gather: block = 16 pos, thread = (pos_local, c8) --------------------
__global__ __launch_bounds__(256) void k_gather(
    const __half* __restrict__ vH, const float* __restrict__ crd,
    const float* __restrict__ attw, float* __restrict__ out) {
  __shared__ float crdS[2 * 16 * 18];
  __shared__ float wS[16 * 36];
  int b = blockIdx.x >> 10;               // 1024 blocks per batch
  int p0 = (blockIdx.x & 1023) * 16;      // local pos base

  {
    const float* cg0 = crd + ((size_t)(b * 2 + 0) * 16384 + p0) * 18;
    const float* cg1 = crd + ((size_t)(b * 2 + 1) * 16384 + p0) * 18;
    for (int i = threadIdx.x; i < 288; i += 256) {
      crdS[i] = cg0[i];
      crdS[288 + i] = cg1[i];
    }
    const float* wg = attw + ((size_t)b * 16384 + p0) * 36;
    for (int i = threadIdx.x; i < 576; i += 256) wS[i] = wg[i];
  }
  __syncthreads();

  int pl = threadIdx.x >> 4, c8 = threadIdx.x & 15;
  int g = c8 >> 3, h = c8 >> 2, ch = c8 * 8;
  int pos = p0 + pl;
  const __half* vb = vH + (size_t)b * 4096 * 128 + ch;
  const float* cw = crdS + g * 288 + pl * 18;
  const float* ww = wS + pl * 36 + h * 9;

  float acc[8] = {};
  #pragma unroll
  for (int kp = 0; kp < 9; ++kp) {
    float iy = cw[2 * kp], ix = cw[2 * kp + 1];
    float yf = floorf(iy), xf = floorf(ix);
    float wy = iy - yf, wx = ix - xf;
    int y0 = (int)yf, x0 = (int)xf;
    float aw = ww[kp];
    #pragma unroll
    for (int dy = 0; dy < 2; ++dy) {
      int yy = y0 + dy;
      float wyv = dy ? wy : 1.f - wy;
      #pragma unroll
      for (int dx = 0; dx < 2; ++dx) {
        int xx = x0 + dx;
        bool valid = ((unsigned)yy < 64u) && ((unsigned)xx < 64u);
        float w = valid ? aw * wyv * (dx ? wx : 1.f - wx) : 0.f;
        int idx = valid ? yy * 64 + xx : 0;
        float4 raw = *(const float4*)(vb + (size_t)idx * 128);
        float f[8];
        unpack8(raw, f);
        #pragma unroll
        for (int i = 0; i < 8; ++i) acc[i] = fmaf(w, f[i], acc[i]);
      }
    }
  }

  float* op = out + ((size_t)b * 128 + ch) * 16384 + pos;
  #pragma unroll
  for (int i = 0; i < 8; ++i) op[(size_t)i * 16384] = acc[i];
}

}  // namespace

extern "C" void kernel_launch(void* const* d_in, const int* in_sizes, int n_in,
                              void* d_out, int out_size, void* d_ws, size_t ws_size,
                              hipStream_t stream) {
  const float* x    = (const float*)d_in[0];
  const float* lnw  = (const float*)d_in[1];
  const float* lnb  = (const float*)d_in[2];
  const float* wq   = (const float*)d_in[3];
  const float* wk   = (const float*)d_in[4];
  const float* dww  = (const float*)d_in[5];
  const float* olnw = (const float*)d_in[6];
  const float* olnb = (const float*)d_in[7];
  const float* offw = (const float*)d_in[8];
  const float* offb = (const float*)d_in[9];
  const float* rpb  = (const float*)d_in[10];
  float* outp = (float*)d_out;

  int B = in_sizes[0] / (128 * 64 * 64);
  size_t nb = (size_t)B * 4096;   // input positions
  size_t np = (size_t)B * 16384;  // output positions

  char* w8 = (char*)d_ws;
  __half* vH  = (__half*)w8;  w8 += nb * 128 * 2;
  __half* kH  = (__half*)w8;  w8 += nb * 32 * 2;
  float*  qT  = (float*)w8;   w8 += nb * 32 * 4;
  float*  qrT = (float*)w8;   w8 += np * 32 * 4;
  float*  tT  = (float*)w8;   w8 += np * 32 * 4;
  float*  crd = (float*)w8;   w8 += np * 2 * 18 * 4;
  float*  attw= (float*)w8;   w8 += np * 36 * 4;
  float*  wT  = (float*)w8;   w8 += 2592 * 4;
  float*  dwT = (float*)w8;   w8 += 144 * 4;
  float*  wqT = (float*)w8;   w8 += 4096 * 4;
  float*  wkT = (float*)w8;   w8 += 4096 * 4;

  hipLaunchKernelGGL(k_repack, dim3(1), dim3(256), 0, stream,
                     offw, dww, wq, wk, wT, dwT, wqT, wkT);
  hipLaunchKernelGGL(k_transpose, dim3(B * 64), dim3(256), 0, stream, x, vH);
  hipLaunchKernelGGL(k_lnproj, dim3(B * 64), dim3(256), 0, stream,
                     x, lnw, lnb, wqT, wkT, qT, kH);
  hipLaunchKernelGGL(k_resize, dim3(B * 64), dim3(256), 0, stream, qT, qrT);
  hipLaunchKernelGGL(k_dwln, dim3(B * 64), dim3(256), 0, stream, qrT, dwT, olnw, olnb, tT);
  hipLaunchKernelGGL(k_off, dim3(B * 64), dim3(256), 0, stream, tT, wT, offb, crd);
  hipLaunchKernelGGL(k_wgt, dim3(B * 128), dim3(256), 0, stream,
                     qrT, kH, crd, rpb, attw);
  hipLaunchKernelGGL(k_gather, dim3(B * 1024), dim3(256), 0, stream,
                     vH, crd, attw, outp);
}

// Round 4
// 149.393 us; speedup vs baseline: 1.8765x; 1.8765x over previous
//
#include <hip/hip_runtime.h>
#include <hip/hip_fp16.h>
#include <cstdint>
#include <cstddef>

#define DEV __device__ __forceinline__

namespace {

constexpr float SCALE  = 0.35355339059327373f;  // 8^-0.5
constexpr float RATIO  = 63.0f / 127.0f;        // grid->input scale
constexpr float RANGEF = 11.0f;
constexpr float EPS    = 1e-6f;

DEV void fax(float4& a, float s, const float4& b) {
  a.x = fmaf(s, b.x, a.x); a.y = fmaf(s, b.y, a.y);
  a.z = fmaf(s, b.z, a.z); a.w = fmaf(s, b.w, a.w);
}
DEV void unpack8(float4 raw, float* f) {
  union { float4 v; __half2 h[4]; } u; u.v = raw;
  #pragma unroll
  for (int j = 0; j < 4; ++j) {
    float2 t = __half22float2(u.h[j]);
    f[2 * j] = t.x; f[2 * j + 1] = t.y;
  }
}

// ---- repack weights -------------------------------------------------------
// wT2[((tap*2+h)*16+j)*9 + i] = off_w[(h*9+i)*144 + j*9 + tap]
// dwT[tap*16+j]=dw_w[j][tap]; wqT[c*32+o]=wq[o*128+c]; wkT same.
__global__ __launch_bounds__(256) void k_repack(
    const float* __restrict__ offw, const float* __restrict__ dww,
    const float* __restrict__ wq, const float* __restrict__ wk,
    float* __restrict__ wT2, float* __restrict__ dwT,
    float* __restrict__ wqT, float* __restrict__ wkT) {
  for (int idx = threadIdx.x; idx < 18 * 16 * 9; idx += 256) {
    int o = idx / 144, j = (idx / 9) % 16, tap = idx % 9;
    int h = o / 9, i = o % 9;
    wT2[((tap * 2 + h) * 16 + j) * 9 + i] = offw[idx];
  }
  for (int idx = threadIdx.x; idx < 144; idx += 256) {
    int j = idx / 9, tap = idx % 9;
    dwT[tap * 16 + j] = dww[idx];
  }
  for (int idx = threadIdx.x; idx < 4096; idx += 256) {
    int c = idx >> 5, o = idx & 31;
    wqT[c * 32 + o] = wq[o * 128 + c];
    wkT[c * 32 + o] = wk[o * 128 + c];
  }
}

// ---- transpose x (B,128,64,64) -> vH fp16 (B,4096,128) ---------------------
__global__ __launch_bounds__(256) void k_transpose(const float* __restrict__ x,
                                                   __half* __restrict__ vH) {
  __shared__ float tile[128 * 65];
  int b = blockIdx.x >> 6, y = blockIdx.x & 63;
  const float* xp = x + (size_t)b * 128 * 4096 + (size_t)y * 64;
  int xc = threadIdx.x & 63, cb = threadIdx.x >> 6;
  #pragma unroll
  for (int i = 0; i < 32; ++i) {
    int c = cb * 32 + i;
    tile[c * 65 + xc] = xp[(size_t)c * 4096 + xc];
  }
  __syncthreads();
  int p = threadIdx.x >> 2, c0 = (threadIdx.x & 3) * 32;
  __half* op = vH + ((size_t)b * 4096 + (size_t)y * 64 + p) * 128 + c0;
  #pragma unroll
  for (int i = 0; i < 32; i += 8) {
    union { float4 f; __half2 h[4]; } u;
    #pragma unroll
    for (int j = 0; j < 4; ++j)
      u.h[j] = __floats2half2_rn(tile[(c0 + i + 2 * j) * 65 + p],
                                 tile[(c0 + i + 2 * j + 1) * 65 + p]);
    *(float4*)(op + i) = u.f;
  }
}

// ---- channel-LN + q/k projection (16 outputs per thread) -------------------
__global__ __launch_bounds__(256) void k_lnproj(
    const float* __restrict__ x, const float* __restrict__ lnw,
    const float* __restrict__ lnb, const float* __restrict__ wqT,
    const float* __restrict__ wkT, float* __restrict__ qT,
    __half* __restrict__ kH) {
  int sub = blockIdx.x & 3;
  int isk = sub >> 1, oh = sub & 1;
  int pos = (blockIdx.x >> 2) * 256 + threadIdx.x;  // [0, B*4096)
  int b = pos >> 12, sp = pos & 4095;
  const float* xp = x + (size_t)b * 128 * 4096 + sp;

  float s = 0.f, ss = 0.f;
  #pragma unroll
  for (int c = 0; c < 128; ++c) {
    float v = xp[(size_t)c * 4096];
    s += v; ss = fmaf(v, v, ss);
  }
  float mean = s * (1.f / 128.f);
  float var = ss * (1.f / 128.f) - mean * mean;
  float rstd = rsqrtf(var + EPS);

  const float* w = (isk ? wkT : wqT) + oh * 16;
  float acc[16];
  #pragma unroll
  for (int o = 0; o < 16; ++o) acc[o] = 0.f;
  #pragma unroll 4
  for (int c = 0; c < 128; ++c) {
    float xn = (xp[(size_t)c * 4096] - mean) * rstd * lnw[c] + lnb[c];
    const float* wr = w + c * 32;
    #pragma unroll
    for (int o = 0; o < 16; ++o) acc[o] = fmaf(wr[o], xn, acc[o]);
  }
  if (!isk) {
    float* op = qT + (size_t)pos * 32 + oh * 16;
    #pragma unroll
    for (int i = 0; i < 16; i += 4)
      *(float4*)(op + i) = make_float4(acc[i], acc[i + 1], acc[i + 2], acc[i + 3]);
  } else {
    __half* op = kH + (size_t)pos * 32 + oh * 16;
    #pragma unroll
    for (int i = 0; i < 16; i += 8) {
      union { float4 f; __half2 h[4]; } u;
      #pragma unroll
      for (int j = 0; j < 4; ++j)
        u.h[j] = __floats2half2_rn(acc[i + 2 * j], acc[i + 2 * j + 1]);
      *(float4*)(op + i) = u.f;
    }
  }
}

// ---- bilinear 64->128 align_corners resize: qT -> qrT ----------------------
__global__ __launch_bounds__(256) void k_resize(const float* __restrict__ qT,
                                                float* __restrict__ qrT) {
  int tid = blockIdx.x * 256 + threadIdx.x;
  int b = tid >> 14, rem = tid & 16383;
  int oy = rem >> 7, ox = rem & 127;
  float ys = oy * RATIO, xs = ox * RATIO;
  float yf = floorf(ys), xf = floorf(xs);
  int y0 = (int)yf, x0 = (int)xf;
  int y1 = min(y0 + 1, 63), x1 = min(x0 + 1, 63);
  float wy = ys - yf, wx = xs - xf;
  const float4* p00 = (const float4*)(qT + ((size_t)b * 4096 + y0 * 64 + x0) * 32);
  const float4* p01 = (const float4*)(qT + ((size_t)b * 4096 + y0 * 64 + x1) * 32);
  const float4* p10 = (const float4*)(qT + ((size_t)b * 4096 + y1 * 64 + x0) * 32);
  const float4* p11 = (const float4*)(qT + ((size_t)b * 4096 + y1 * 64 + x1) * 32);
  float w00 = (1.f - wy) * (1.f - wx), w01 = (1.f - wy) * wx;
  float w10 = wy * (1.f - wx), w11 = wy * wx;
  float4* op = (float4*)(qrT + ((size_t)b * 16384 + rem) * 32);
  #pragma unroll
  for (int i = 0; i < 8; ++i) {
    float4 r = {0.f, 0.f, 0.f, 0.f};
    fax(r, w00, p00[i]); fax(r, w01, p01[i]);
    fax(r, w10, p10[i]); fax(r, w11, p11[i]);
    op[i] = r;
  }
}

// ---- depthwise 3x3 + group channel-LN + SiLU: qrT -> tT --------------------
__global__ __launch_bounds__(256) void k_dwln(
    const float* __restrict__ qrT, const float* __restrict__ dwT,
    const float* __restrict__ olnw, const float* __restrict__ olnb,
    float* __restrict__ tT) {
  int tid = blockIdx.x * 256 + threadIdx.x;
  int b = tid >> 14, rem = tid & 16383;
  int oy = rem >> 7, ox = rem & 127;
  float4 a[8] = {};
  #pragma unroll
  for (int kh = 0; kh < 3; ++kh) {
    int ty = oy + kh - 1;
    if (ty < 0 || ty >= 128) continue;
    #pragma unroll
    for (int kw = 0; kw < 3; ++kw) {
      int tx = ox + kw - 1;
      if (tx < 0 || tx >= 128) continue;
      int tap = kh * 3 + kw;
      const float4* p =
          (const float4*)(qrT + ((size_t)b * 16384 + (size_t)ty * 128 + tx) * 32);
      #pragma unroll
      for (int i = 0; i < 8; ++i) {
        float4 v = p[i];
        const float* dw = dwT + tap * 16 + (i & 3) * 4;
        a[i].x = fmaf(dw[0], v.x, a[i].x);
        a[i].y = fmaf(dw[1], v.y, a[i].y);
        a[i].z = fmaf(dw[2], v.z, a[i].z);
        a[i].w = fmaf(dw[3], v.w, a[i].w);
      }
    }
  }
  float4* op = (float4*)(tT + ((size_t)b * 16384 + rem) * 32);
  #pragma unroll
  for (int g = 0; g < 2; ++g) {
    float s = 0.f;
    #pragma unroll
    for (int i = 0; i < 4; ++i) {
      float4 v = a[g * 4 + i];
      s += v.x + v.y + v.z + v.w;
    }
    float mean = s * (1.f / 16.f);
    float var = 0.f;
    #pragma unroll
    for (int i = 0; i < 4; ++i) {
      float4 v = a[g * 4 + i];
      var += (v.x - mean) * (v.x - mean) + (v.y - mean) * (v.y - mean) +
             (v.z - mean) * (v.z - mean) + (v.w - mean) * (v.w - mean);
    }
    float rstd = rsqrtf(var * (1.f / 16.f) + EPS);
    #pragma unroll
    for (int i = 0; i < 4; ++i) {
      float4 v = a[g * 4 + i];
      int j0 = i * 4;
      float4 r;
      r.x = (v.x - mean) * rstd * olnw[j0 + 0] + olnb[j0 + 0];
      r.y = (v.y - mean) * rstd * olnw[j0 + 1] + olnb[j0 + 1];
      r.z = (v.z - mean) * rstd * olnw[j0 + 2] + olnb[j0 + 2];
      r.w = (v.w - mean) * rstd * olnw[j0 + 3] + olnb[j0 + 3];
      r.x = r.x / (1.f + expf(-r.x));
      r.y = r.y / (1.f + expf(-r.y));
      r.z = r.z / (1.f + expf(-r.z));
      r.w = r.w / (1.f + expf(-r.w));
      op[g * 4 + i] = r;
    }
  }
}

// ---- 16->18 3x3 conv + tanh*RANGE + abs coords: tT -> crd ------------------
// thread = (group-position, output-half). 128 pos + 2 halves per block.
// h uniform per wave (bit7 of threadIdx) -> readfirstlane -> scalar weights.
__global__ __launch_bounds__(256) void k_off(
    const float* __restrict__ tT, const float* __restrict__ wT2,
    const float* __restrict__ offb, float* __restrict__ crd) {
  int tid = blockIdx.x * 128 + (threadIdx.x & 127);  // [0, B*2*16384)
  int h = __builtin_amdgcn_readfirstlane(threadIdx.x >> 7);
  int bg = tid >> 14, rem = tid & 16383;
  int oy = rem >> 7, ox = rem & 127;
  int b = bg >> 1, g = bg & 1;

  float a[9];
  #pragma unroll
  for (int i = 0; i < 9; ++i) a[i] = 0.f;

  #pragma unroll
  for (int kh = 0; kh < 3; ++kh) {
    int ty = oy + kh - 1;
    if (ty < 0 || ty >= 128) continue;
    const float* base = tT + ((size_t)b * 16384 + (size_t)ty * 128) * 32 + g * 16;
    #pragma unroll
    for (int kw = 0; kw < 3; ++kw) {
      int tap = kh * 3 + kw;
      int tx = ox + kw - 1;
      if ((unsigned)tx >= 128u) continue;
      const float4* p = (const float4*)(base + (size_t)tx * 32);
      float4 A0 = p[0], A1 = p[1], A2 = p[2], A3 = p[3];
      float in[16] = {A0.x, A0.y, A0.z, A0.w, A1.x, A1.y, A1.z, A1.w,
                      A2.x, A2.y, A2.z, A2.w, A3.x, A3.y, A3.z, A3.w};
      const float* wrow = wT2 + (size_t)(tap * 2 + h) * 144;
      #pragma unroll
      for (int j = 0; j < 16; ++j) {
        float f = in[j];
        #pragma unroll
        for (int i = 0; i < 9; ++i)
          a[i] = fmaf(wrow[j * 9 + i], f, a[i]);
      }
    }
  }

  const float* bb = offb + h * 9;
  float* cp = crd + (size_t)tid * 18 + h * 9;
  #pragma unroll
  for (int i = 0; i < 9; ++i) {
    int o = h * 9 + i;
    int kp = o >> 1;
    float basec = (o & 1) ? (float)(kp % 3 - 1 + ox) : (float)(kp / 3 - 1 + oy);
    cp[i] = fmaf(tanhf(a[i] + bb[i]), RANGEF, basec) * RATIO;
  }
}

// ---- attention weights: thread = (b,g,pos), both heads of the group --------
__global__ __launch_bounds__(256) void k_wgt(
    const float* __restrict__ qrT, const __half* __restrict__ kH,
    const float* __restrict__ crd, const float* __restrict__ rpb,
    float* __restrict__ attw) {
  int tid = blockIdx.x * 256 + threadIdx.x;  // [0, B*2*16384)
  int pos = tid & 16383;
  int bg = tid >> 14;
  int g = bg & 1, b = bg >> 1;

  float q[16];
  const float4* qp = (const float4*)(qrT + ((size_t)b * 16384 + pos) * 32 + g * 16);
  #pragma unroll
  for (int i = 0; i < 4; ++i) {
    float4 v = qp[i];
    q[4 * i + 0] = v.x * SCALE; q[4 * i + 1] = v.y * SCALE;
    q[4 * i + 2] = v.z * SCALE; q[4 * i + 3] = v.w * SCALE;
  }
  const float* cp = crd + ((size_t)bg * 16384 + pos) * 18;
  const __half* kb = kH + (size_t)b * 4096 * 32 + g * 16;

  float l0[9], l1[9];
  #pragma unroll
  for (int kp = 0; kp < 9; ++kp) {
    float iy = cp[2 * kp], ix = cp[2 * kp + 1];
    float yf = floorf(iy), xf = floorf(ix);
    float wy = iy - yf, wx = ix - xf;
    int y0 = (int)yf, x0 = (int)xf;
    float a0 = 0.f, a1 = 0.f;
    #pragma unroll
    for (int dy = 0; dy < 2; ++dy) {
      int yy = y0 + dy;
      float wyv = dy ? wy : 1.f - wy;
      #pragma unroll
      for (int dx = 0; dx < 2; ++dx) {
        int xx = x0 + dx;
        bool valid = ((unsigned)yy < 64u) && ((unsigned)xx < 64u);
        float w = valid ? wyv * (dx ? wx : 1.f - wx) : 0.f;
        int idx = valid ? yy * 64 + xx : 0;
        const float4* kr = (const float4*)(kb + (size_t)idx * 32);
        float kf[16];
        unpack8(kr[0], kf); unpack8(kr[1], kf + 8);
        float d0 = 0.f, d1 = 0.f;
        #pragma unroll
        for (int e = 0; e < 8; ++e) {
          d0 = fmaf(q[e], kf[e], d0);
          d1 = fmaf(q[8 + e], kf[8 + e], d1);
        }
        a0 = fmaf(w, d0, a0);
        a1 = fmaf(w, d1, a1);
      }
    }
    const float* rp0 = rpb + (size_t)((2 * g) * 9 + kp) * 8;
    const float* rp1 = rpb + (size_t)((2 * g + 1) * 9 + kp) * 8;
    #pragma unroll
    for (int e = 0; e < 8; ++e) {
      a0 = fmaf(q[e], rp0[e], a0);
      a1 = fmaf(q[8 + e], rp1[e], a1);
    }
    l0[kp] = a0; l1[kp] = a1;
  }

  float m0 = l0[0], m1 = l1[0];
  #pragma unroll
  for (int kp = 1; kp < 9; ++kp) { m0 = fmaxf(m0, l0[kp]); m1 = fmaxf(m1, l1[kp]); }
  float s0 = 0.f, s1 = 0.f;
  #pragma unroll
  for (int kp = 0; kp < 9; ++kp) {
    l0[kp] = expf(l0[kp] - m0); s0 += l0[kp];
    l1[kp] = expf(l1[kp] - m1); s1 += l1[kp];
  }
  float i0 = 1.f / s0, i1 = 1.f / s1;
  float* wp = attw + ((size_t)b * 16384 + pos) * 36 + g * 18;
  #pragma unroll
  for (int kp = 0; kp < 9; ++kp) {
    wp[kp] = l0[kp] * i0;
    wp[9 + kp] = l1[kp] * i1;
  }
}

// ---- v gather: block = 16 pos, thread = (pos_local, c8) --------------------
__global__ __launch_bounds__(256) void k_gather(
    const __half* __restrict__ vH, const float* __restrict__ crd,
    const float* __restrict__ attw, float* __restrict__ out) {
  __shared__ float crdS[2 * 16 * 18];
  __shared__ float wS[16 * 36];
  int b = blockIdx.x >> 10;               // 1024 blocks per batch
  int p0 = (blockIdx.x & 1023) * 16;      // local pos base

  {
    const float* cg0 = crd + ((size_t)(b * 2 + 0) * 16384 + p0) * 18;
    const float* cg1 = crd + ((size_t)(b * 2 + 1) * 16384 + p0) * 18;
    for (int i = threadIdx.x; i < 288; i += 256) {
      crdS[i] = cg0[i];
      crdS[288 + i] = cg1[i];
    }
    const float* wg = attw + ((size_t)b * 16384 + p0) * 36;
    for (int i = threadIdx.x; i < 576; i += 256) wS[i] = wg[i];
  }
  __syncthreads();

  int pl = threadIdx.x >> 4, c8 = threadIdx.x & 15;
  int g = c8 >> 3, h = c8 >> 2, ch = c8 * 8;
  int pos = p0 + pl;
  const __half* vb = vH + (size_t)b * 4096 * 128 + ch;
  const float* cw = crdS + g * 288 + pl * 18;
  const float* ww = wS + pl * 36 + h * 9;

  float acc[8] = {};
  #pragma unroll
  for (int kp = 0; kp < 9; ++kp) {
    float iy = cw[2 * kp], ix = cw[2 * kp + 1];
    float yf = floorf(iy), xf = floorf(ix);
    float wy = iy - yf, wx = ix - xf;
    int y0 = (int)yf, x0 = (int)xf;
    float aw = ww[kp];
    #pragma unroll
    for (int dy = 0; dy < 2; ++dy) {
      int yy = y0 + dy;
      float wyv = dy ? wy : 1.f - wy;
      #pragma unroll
      for (int dx = 0; dx < 2; ++dx) {
        int xx = x0 + dx;
        bool valid = ((unsigned)yy < 64u) && ((unsigned)xx < 64u);
        float w = valid ? aw * wyv * (dx ? wx : 1.f - wx) : 0.f;
        int idx = valid ? yy * 64 + xx : 0;
        float4 raw = *(const float4*)(vb + (size_t)idx * 128);
        float f[8];
        unpack8(raw, f);
        #pragma unroll
        for (int i = 0; i < 8; ++i) acc[i] = fmaf(w, f[i], acc[i]);
      }
    }
  }

  float* op = out + ((size_t)b * 128 + ch) * 16384 + pos;
  #pragma unroll
  for (int i = 0; i < 8; ++i) op[(size_t)i * 16384] = acc[i];
}

}  // namespace

extern "C" void kernel_launch(void* const* d_in, const int* in_sizes, int n_in,
                              void* d_out, int out_size, void* d_ws, size_t ws_size,
                              hipStream_t stream) {
  const float* x    = (const float*)d_in[0];
  const float* lnw  = (const float*)d_in[1];
  const float* lnb  = (const float*)d_in[2];
  const float* wq   = (const float*)d_in[3];
  const float* wk   = (const float*)d_in[4];
  const float* dww  = (const float*)d_in[5];
  const float* olnw = (const float*)d_in[6];
  const float* olnb = (const float*)d_in[7];
  const float* offw = (const float*)d_in[8];
  const float* offb = (const float*)d_in[9];
  const float* rpb  = (const float*)d_in[10];
  float* outp = (float*)d_out;

  int B = in_sizes[0] / (128 * 64 * 64);
  size_t nb = (size_t)B * 4096;   // input positions
  size_t np = (size_t)B * 16384;  // output positions

  char* w8 = (char*)d_ws;
  __half* vH  = (__half*)w8;  w8 += nb * 128 * 2;
  __half* kH  = (__half*)w8;  w8 += nb * 32 * 2;
  float*  qT  = (float*)w8;   w8 += nb * 32 * 4;
  float*  qrT = (float*)w8;   w8 += np * 32 * 4;
  float*  tT  = (float*)w8;   w8 += np * 32 * 4;
  float*  crd = (float*)w8;   w8 += np * 2 * 18 * 4;
  float*  attw= (float*)w8;   w8 += np * 36 * 4;
  float*  wT2 = (float*)w8;   w8 += 2592 * 4;
  float*  dwT = (float*)w8;   w8 += 144 * 4;
  float*  wqT = (float*)w8;   w8 += 4096 * 4;
  float*  wkT = (float*)w8;   w8 += 4096 * 4;

  hipLaunchKernelGGL(k_repack, dim3(1), dim3(256), 0, stream,
                     offw, dww, wq, wk, wT2, dwT, wqT, wkT);
  hipLaunchKernelGGL(k_transpose, dim3(B * 64), dim3(256), 0, stream, x, vH);
  hipLaunchKernelGGL(k_lnproj, dim3(B * 64), dim3(256), 0, stream,
                     x, lnw, lnb, wqT, wkT, qT, kH);
  hipLaunchKernelGGL(k_resize, dim3(B * 64), dim3(256), 0, stream, qT, qrT);
  hipLaunchKernelGGL(k_dwln, dim3(B * 64), dim3(256), 0, stream, qrT, dwT, olnw, olnb, tT);
  hipLaunchKernelGGL(k_off, dim3(B * 256), dim3(256), 0, stream, tT, wT2, offb, crd);
  hipLaunchKernelGGL(k_wgt, dim3(B * 128), dim3(256), 0, stream,
                     qrT, kH, crd, rpb, attw);
  hipLaunchKernelGGL(k_gather, dim3(B * 1024), dim3(256), 0, stream,
                     vH, crd, attw, outp);
}